// Round 9
// baseline (39.718 us; speedup 1.0000x reference)
//
#include <hip/hip_runtime.h>
#include <math.h>

typedef float v2f __attribute__((ext_vector_type(2)));

#define HALF 64
#define DFE  128
#define B    4096          // HALF*HALF
#define NF   8192          // 2*B
#define GRAM_BLOCKS  32
#define SAME_BLOCKS  1024  // 8 rows each (both halves)
#define CROSS_BLOCKS 1024  // 4 src rows each x full trgt half
#define PAIR_BLOCKS  (SAME_BLOCKS + CROSS_BLOCKS)
#define LOG2E 1.4426950408889634074
#define XPAD 130           // f32 row stride in gram LDS (2-mod-32 -> <=4-way banks)

// K(u)=u+u^2+u^4+u^8+u^16, u=2^{-(d*d)}; d pre-scaled by sqrt(log2e/(4*Dm)).
// Packed f32: ~10 pk-ops + 2 v_exp_f32 per TWO pairs.
// d=1e18 sentinel => exp2(-1e36)=0 exactly => pair contributes 0.
__device__ __forceinline__ void kern_d(v2f d, v2f& a1, v2f& a2, v2f& a3) {
    const v2f m = d * d;
    v2f u;
    u.x = __builtin_amdgcn_exp2f(-m.x);
    u.y = __builtin_amdgcn_exp2f(-m.y);
    const v2f u2 = u * u;
    const v2f u4 = u2 * u2;
    const v2f u8 = u4 * u4;
    a1 += u + u2;
    a2 += u4 + u8;
    a3 += u8 * u8;     // + u^16
}

// ---------------- K1: cosine Gram (f64 dots of f32 rows) -------------------
// f_ij = R_ij * inv_i * inv_j, inv = 1/max(sqrt(R_ii),1e-8). No f64 LDS copy.
__global__ __launch_bounds__(256) void gram_kernel(const float* __restrict__ feats,
                                                   float* __restrict__ ff,
                                                   double* __restrict__ pm,
                                                   unsigned int* __restrict__ ctr) {
    __shared__ float  xs[HALF * XPAD];   // ~33 KB padded f32
    __shared__ double nrmp[256];
    __shared__ double inv[HALF];
    __shared__ double wred[8];
    const int h   = blockIdx.x >> 4;
    const int seg = blockIdx.x & 15;
    const int tid = threadIdx.x;
    if (blockIdx.x == 0 && tid == 0) atomicExch(ctr, 0u);  // per-call reset
    const float* base = feats + h * HALF * DFE;

    // stage: float4 global loads -> float2 LDS writes (stride-130 rows)
    #pragma unroll
    for (int m = 0; m < 8; ++m) {
        const int idx = tid + 256 * m;            // 2048 float4s
        const int r = idx >> 5, s = (idx & 31) << 2;
        const float4 v = *(const float4*)(base + r * DFE + s);
        *(float2*)&xs[r * XPAD + s]     = make_float2(v.x, v.y);
        *(float2*)&xs[r * XPAD + s + 2] = make_float2(v.z, v.w);
    }
    __syncthreads();

    // norms: 4 threads per row (32 elems each), f64 partials
    {
        const int r = tid & 63, hh = tid >> 6;
        const float* row = &xs[r * XPAD + 32 * hh];
        double s0 = 0.0, s1 = 0.0;
        #pragma unroll
        for (int k = 0; k < 32; k += 2) {
            const float2 v = *(const float2*)&row[k];
            s0 = fma((double)v.x, (double)v.x, s0);
            s1 = fma((double)v.y, (double)v.y, s1);
        }
        nrmp[hh * 64 + r] = s0 + s1;
    }
    __syncthreads();
    if (tid < HALF) {
        const double s = (nrmp[tid] + nrmp[64 + tid]) + (nrmp[128 + tid] + nrmp[192 + tid]);
        inv[tid] = 1.0 / fmax(sqrt(s), 1e-8);
    }
    __syncthreads();

    // dot: one output per thread; i wave-uniform (broadcast reads), j per-lane
    const int p = seg * 256 + tid;
    const int i = p >> 6, j = p & 63;
    const float* ri = &xs[i * XPAD];
    const float* rj = &xs[j * XPAD];
    double s0 = 0.0, s1 = 0.0;
    #pragma unroll 8
    for (int k = 0; k < DFE; k += 2) {
        const float2 a = *(const float2*)&ri[k];
        const float2 b = *(const float2*)&rj[k];
        s0 = fma((double)a.x, (double)b.x, s0);
        s1 = fma((double)a.y, (double)b.y, s1);
    }
    const double v = (s0 + s1) * inv[i] * inv[j];
    ff[h * B + p] = (float)v;              // f32 for the pair phase

    // moments (f64): in-wave butterfly, then 4 wave-partials via LDS
    double r1 = v, r2 = v * v;
    #pragma unroll
    for (int msk = 1; msk < 64; msk <<= 1) {
        r1 += __shfl_xor(r1, msk);
        r2 += __shfl_xor(r2, msk);
    }
    if ((tid & 63) == 0) { wred[(tid >> 6) * 2] = r1; wred[(tid >> 6) * 2 + 1] = r2; }
    __syncthreads();
    if (tid == 0) {
        pm[2 * blockIdx.x]     = (wred[0] + wred[2]) + (wred[4] + wred[6]);
        pm[2 * blockIdx.x + 1] = (wred[1] + wred[3]) + (wred[5] + wred[7]);
    }
}

// ---------------- K2: pair sums + fused deterministic final ----------------
// Same blocks (bid<1024): 8 rows in VGPRs, uniform window c in [8,2055]
//   (NO predication in main loop); 36 over-counted g>=2048 pairs recomputed
//   into negative accumulators; edge adds g in [1,7-rho] (28) + straddle
//   g=2048 (8, first-half blocks only).       [coverage verified in R8]
// Cross blocks: 4 src rows x full trgt half.
// Final: block partials published via DEVICE-SCOPE atomicExch (NO
//   __threadfence — R5 lesson: fence = per-block L2 writeback, +70us).
//   asm data-dep orders exch < counter-add. Elected last block atomic-reads
//   all 2048 partials and reduces in FIXED order -> bitwise deterministic.
__global__ __launch_bounds__(256, 8) void pair_kernel(const float* __restrict__ ff,
                                                      const double* __restrict__ pm,
                                                      double* __restrict__ partials,
                                                      unsigned int* __restrict__ ctr,
                                                      float* __restrict__ out) {
    __shared__ float  fs[B];       // 16 KB raw half
    __shared__ float  sclS;
    __shared__ double wred[4];
    __shared__ int    lastS;
    const int tid = threadIdx.x;
    const int bid = blockIdx.x;
    const bool same = bid < SAME_BLOCKS;
    const int  r0g  = same ? (bid << 3) : 0;
    const float* src = same ? (ff + (r0g & 4096)) : (ff + B);

    {   // stage 16 KB (raw, scale applied at fragment load)
        const float4* s4 = (const float4*)src;
        float4* d4 = (float4*)fs;
        #pragma unroll
        for (int k = 0; k < 4; ++k) d4[tid + 256 * k] = s4[tid + 256 * k];
    }
    if (tid < 64) {   // wave 0: scl from gram moments, hidden under staging
        double s = pm[tid];
        #pragma unroll
        for (int msk = 2; msk <= 32; msk <<= 1) s += __shfl_xor(s, msk);
        const double o = __shfl_xor(s, 1);     // lane0: s=sum, o=sumsq
        if (tid == 0) {
            const double m1 = s * (1.0 / NF);
            const double m2 = o * (1.0 / NF);
            const double Dm = 2.0 * (m2 - m1 * m1);
            sclS = (float)sqrt(LOG2E / (4.0 * Dm));
        }
    }
    __syncthreads();
    const float scl = sclS;

    v2f a1 = {0.f,0.f}, a2 = {0.f,0.f}, a3 = {0.f,0.f};
    v2f n1 = {0.f,0.f}, n2 = {0.f,0.f}, n3 = {0.f,0.f};

    if (same) {
        const int r0l = r0g & 4095;            // multiple of 8
        v2f fi[4];                             // 8 rows (broadcast LDS reads)
        #pragma unroll
        for (int q = 0; q < 4; ++q) {
            fi[q].x = fs[r0l + 2 * q]     * scl;
            fi[q].y = fs[r0l + 2 * q + 1] * scl;
        }
        const int c0 = 8 + (tid << 3);         // 8 c-values, c in [8,2055]
        const int j0 = (r0l + c0) & 4095;      // 8-aligned -> aligned b128
        float vj[8];
        *(float4*)&vj[0] = *(const float4*)&fs[j0];
        *(float4*)&vj[4] = *(const float4*)&fs[j0 + 4];
        #pragma unroll
        for (int e = 0; e < 8; ++e) {          // fully uniform main loop
            v2f vv; vv.x = vj[e] * scl; vv.y = vj[e] * scl;
            #pragma unroll
            for (int q = 0; q < 4; ++q)
                kern_d(fi[q] - vv, a1, a2, a3);
        }
        if (tid < 18) {
            // subtract the 36 over-counted pairs: c=2048+m (m<8), rho<=m
            v2f d;
            #pragma unroll
            for (int hp = 0; hp < 2; ++hp) {
                const int idx = 2 * tid + hp;              // [0,36)
                const int m   = (int)((sqrtf((float)(8 * idx + 1)) - 1.0f) * 0.5f);
                const int rho = idx - ((m * (m + 1)) >> 1);
                const float dv = (fs[r0l + rho] - fs[(r0l + 2048 + m) & 4095]) * scl;
                if (hp == 0) d.x = dv; else d.y = dv;
            }
            kern_d(d, n1, n2, n3);
            // add: 28 intra-block triangle (g in [1,7-rho]) + 8 straddle g=2048
            v2f d2;
            #pragma unroll
            for (int hp = 0; hp < 2; ++hp) {
                const int idx = 2 * tid + hp;              // [0,36)
                float dv;
                if (idx < 28) {
                    const int m   = (int)((1.0f + sqrtf((float)(1 + 8 * idx))) * 0.5f);
                    const int g   = idx - ((m * (m - 1)) >> 1) + 1;
                    const int rho = m - g;
                    dv = (fs[r0l + rho] - fs[r0l + rho + g]) * scl;
                } else {
                    const int rho = idx - 28;
                    dv = (r0l < 2048)
                       ? (fs[r0l + rho] - fs[r0l + rho + 2048]) * scl : 1e18f;
                }
                if (hp == 0) d2.x = dv; else d2.y = dv;
            }
            kern_d(d2, a1, a2, a3);
        }
    } else {
        const int r0c = (bid - SAME_BLOCKS) << 2;  // 4 src rows
        v2f fi[2];
        #pragma unroll
        for (int q = 0; q < 2; ++q) {
            fi[q].x = ff[r0c + 2 * q]     * scl;
            fi[q].y = ff[r0c + 2 * q + 1] * scl;
        }
        const int c0 = tid << 4;               // 16 contiguous trgt values
        float vj[16];
        #pragma unroll
        for (int k = 0; k < 4; ++k)
            *(float4*)&vj[4 * k] = *(const float4*)&fs[c0 + 4 * k];
        #pragma unroll
        for (int e = 0; e < 16; ++e) {
            v2f vv; vv.x = vj[e] * scl; vv.y = vj[e] * scl;
            #pragma unroll
            for (int q = 0; q < 2; ++q)
                kern_d(fi[q] - vv, a1, a2, a3);
        }
    }

    // block reduce: f64 convert, in-wave butterfly, 4 wave-partials via LDS
    double t = (((double)a1.x + (double)a1.y) + ((double)a2.x + (double)a2.y)
             +  ((double)a3.x + (double)a3.y))
             - (((double)n1.x + (double)n1.y) + ((double)n2.x + (double)n2.y)
             +  ((double)n3.x + (double)n3.y));
    #pragma unroll
    for (int msk = 1; msk < 64; msk <<= 1) t += __shfl_xor(t, msk);
    if ((tid & 63) == 0) wred[tid >> 6] = t;
    __syncthreads();

    if (tid == 0) {
        const double p = (wred[0] + wred[1]) + (wred[2] + wred[3]);
        // publish partial at device-scope coherent point (atomic, NOT fence)
        unsigned long long oldb =
            atomicExch((unsigned long long*)&partials[bid], __double_as_longlong(p));
        // opaque zero derived from oldb: forces vmcnt-wait on the exch
        // completing BEFORE the counter increment is issued
        unsigned lo = (unsigned)oldb;
        asm volatile("v_and_b32 %0, 0, %0" : "+v"(lo));
        const unsigned cnt = atomicAdd(ctr, 1u + lo);
        lastS = (cnt == PAIR_BLOCKS - 1);
    }
    __syncthreads();

    if (lastS) {   // elected last block: fixed-order reduce of all partials
        const int b0 = tid * 8;                 // threads 0-127: same, 128-255: cross
        double s = 0.0;
        #pragma unroll
        for (int k = 0; k < 8; ++k) {
            const unsigned long long bits =
                atomicAdd((unsigned long long*)&partials[b0 + k], 0ull);  // atomic read
            s += __longlong_as_double((long long)bits);
        }
        #pragma unroll
        for (int msk = 1; msk < 64; msk <<= 1) s += __shfl_xor(s, msk);
        if ((tid & 63) == 0) wred[tid >> 6] = s;   // waves 0,1: same; 2,3: cross
        __syncthreads();
        if (tid == 0) {
            const double S_same  = 2.0 * (wred[0] + wred[1]);   // unordered -> ordered
            const double S_cross = 2.0 * (wred[2] + wred[3]);   // one dir -> both
            const double bb = (double)B;
            const double loss = S_same / (bb * (bb - 1.0))
                              - S_cross / (bb * bb)
                              + 2.0 / (bb - 1.0);
            out[0] = (float)loss;
        }
    }
}

extern "C" void kernel_launch(void* const* d_in, const int* in_sizes, int n_in,
                              void* d_out, int out_size, void* d_ws, size_t ws_size,
                              hipStream_t stream) {
    const float* feats = (const float*)d_in[0];
    float* out = (float*)d_out;
    double* ws = (double*)d_ws;

    double*       pm       = ws;                          // 64 doubles
    double*       partials = ws + 64;                     // 2048 doubles
    unsigned int* ctr      = (unsigned int*)(ws + 64 + 2048);   // 1 uint (8B slot)
    float*        ff       = (float*)(ws + 64 + 2048 + 1);      // 8192 floats

    gram_kernel<<<GRAM_BLOCKS, 256, 0, stream>>>(feats, ff, pm, ctr);
    pair_kernel<<<PAIR_BLOCKS, 256, 0, stream>>>(ff, pm, partials, ctr, out);
}

// Round 10
// 24.106 us; speedup vs baseline: 1.6476x; 1.6476x over previous
//
#include <hip/hip_runtime.h>
#include <math.h>

typedef float v2f __attribute__((ext_vector_type(2)));

#define HALF 64
#define DFE  128
#define B    4096          // HALF*HALF
#define NF   8192          // 2*B
#define GRAM_BLOCKS  32
#define SAME_BLOCKS  1024  // 8 rows each (both halves)
#define CROSS_BLOCKS 1024  // 4 src rows each x full trgt half
#define PAIR_BLOCKS  (SAME_BLOCKS + CROSS_BLOCKS)
#define LOG2E 1.4426950408889634074
#define XPAD 130           // f32 row stride in gram LDS (2-mod-32 -> <=4-way banks)

// K(u)=u+u^2+u^4+u^8+u^16, u=2^{-(d*d)}; d pre-scaled by sqrt(log2e/(4*Dm)).
// d=1e18 sentinel => exp2(-1e36)=0 exactly => pair contributes 0.
__device__ __forceinline__ void kern_d(v2f d, v2f& a1, v2f& a2, v2f& a3) {
    const v2f m = d * d;
    v2f u;
    u.x = __builtin_amdgcn_exp2f(-m.x);
    u.y = __builtin_amdgcn_exp2f(-m.y);
    const v2f u2 = u * u;
    const v2f u4 = u2 * u2;
    const v2f u8 = u4 * u4;
    a1 += u + u2;
    a2 += u4 + u8;
    a3 += u8 * u8;     // + u^16
}

// Stage-batched: 4 v2f (8 pairs) per call. All 4 m's, then 8 INDEPENDENT
// v_exp_f32 chains, then power chains, then tree-summed accumulates.
// Purpose: force ~50 live VGPRs / high ILP (R9 post-mortem: compiler
// allocated 20 VGPRs and serialized ~30-cyc dependent chains -> 55% VALU).
__device__ __forceinline__ void kern_b4(v2f d0, v2f d1, v2f d2, v2f d3,
                                        v2f& a1, v2f& a2, v2f& a3) {
    const v2f m0 = d0 * d0, m1 = d1 * d1, m2 = d2 * d2, m3 = d3 * d3;
    v2f u0, u1, u2, u3;
    u0.x = __builtin_amdgcn_exp2f(-m0.x); u0.y = __builtin_amdgcn_exp2f(-m0.y);
    u1.x = __builtin_amdgcn_exp2f(-m1.x); u1.y = __builtin_amdgcn_exp2f(-m1.y);
    u2.x = __builtin_amdgcn_exp2f(-m2.x); u2.y = __builtin_amdgcn_exp2f(-m2.y);
    u3.x = __builtin_amdgcn_exp2f(-m3.x); u3.y = __builtin_amdgcn_exp2f(-m3.y);
    const v2f q0 = u0 * u0, q1 = u1 * u1, q2 = u2 * u2, q3 = u3 * u3;   // u^2
    const v2f r0 = q0 * q0, r1 = q1 * q1, r2 = q2 * q2, r3 = q3 * q3;   // u^4
    const v2f w0 = r0 * r0, w1 = r1 * r1, w2 = r2 * r2, w3 = r3 * r3;   // u^8
    a1 += ((u0 + q0) + (u1 + q1)) + ((u2 + q2) + (u3 + q3));
    a2 += ((r0 + w0) + (r1 + w1)) + ((r2 + w2) + (r3 + w3));
    a3 += ((w0 * w0) + (w1 * w1)) + ((w2 * w2) + (w3 * w3));            // u^16
}

// ---------------- K1: cosine Gram (f64 dots of f32 rows) -------------------
__global__ __launch_bounds__(256) void gram_kernel(const float* __restrict__ feats,
                                                   float* __restrict__ ff,
                                                   double* __restrict__ pm) {
    __shared__ float  xs[HALF * XPAD];   // ~33 KB padded f32
    __shared__ double nrmp[256];
    __shared__ double inv[HALF];
    __shared__ double wred[8];
    const int h   = blockIdx.x >> 4;
    const int seg = blockIdx.x & 15;
    const int tid = threadIdx.x;
    const float* base = feats + h * HALF * DFE;

    // stage: float4 global loads -> float2 LDS writes (stride-130 rows)
    #pragma unroll
    for (int m = 0; m < 8; ++m) {
        const int idx = tid + 256 * m;            // 2048 float4s
        const int r = idx >> 5, s = (idx & 31) << 2;
        const float4 v = *(const float4*)(base + r * DFE + s);
        *(float2*)&xs[r * XPAD + s]     = make_float2(v.x, v.y);
        *(float2*)&xs[r * XPAD + s + 2] = make_float2(v.z, v.w);
    }
    __syncthreads();

    // norms: 4 threads per row (32 elems each), f64 partials
    {
        const int r = tid & 63, hh = tid >> 6;
        const float* row = &xs[r * XPAD + 32 * hh];
        double s0 = 0.0, s1 = 0.0;
        #pragma unroll
        for (int k = 0; k < 32; k += 2) {
            const float2 v = *(const float2*)&row[k];
            s0 = fma((double)v.x, (double)v.x, s0);
            s1 = fma((double)v.y, (double)v.y, s1);
        }
        nrmp[hh * 64 + r] = s0 + s1;
    }
    __syncthreads();
    if (tid < HALF) {
        const double s = (nrmp[tid] + nrmp[64 + tid]) + (nrmp[128 + tid] + nrmp[192 + tid]);
        inv[tid] = 1.0 / fmax(sqrt(s), 1e-8);
    }
    __syncthreads();

    // dot: one output per thread; i wave-uniform (broadcast reads), j per-lane
    const int p = seg * 256 + tid;
    const int i = p >> 6, j = p & 63;
    const float* ri = &xs[i * XPAD];
    const float* rj = &xs[j * XPAD];
    double s0 = 0.0, s1 = 0.0;
    #pragma unroll 8
    for (int k = 0; k < DFE; k += 2) {
        const float2 a = *(const float2*)&ri[k];
        const float2 b = *(const float2*)&rj[k];
        s0 = fma((double)a.x, (double)b.x, s0);
        s1 = fma((double)a.y, (double)b.y, s1);
    }
    const double v = (s0 + s1) * inv[i] * inv[j];
    ff[h * B + p] = (float)v;              // f32 for the pair phase

    // moments (f64): in-wave butterfly, then 4 wave-partials via LDS
    double r1 = v, r2 = v * v;
    #pragma unroll
    for (int msk = 1; msk < 64; msk <<= 1) {
        r1 += __shfl_xor(r1, msk);
        r2 += __shfl_xor(r2, msk);
    }
    if ((tid & 63) == 0) { wred[(tid >> 6) * 2] = r1; wred[(tid >> 6) * 2 + 1] = r2; }
    __syncthreads();
    if (tid == 0) {
        pm[2 * blockIdx.x]     = (wred[0] + wred[2]) + (wred[4] + wred[6]);
        pm[2 * blockIdx.x + 1] = (wred[1] + wred[3]) + (wred[5] + wred[7]);
    }
}

// ---------------- K2: pair sums, 2048 uniform blocks -----------------------
// Same blocks (bid<1024): 8 rows in VGPRs, uniform window c in [8,2055]
//   (NO predication in main loop); 36 over-counted g>=2048 pairs recomputed
//   into negative accumulators; edge adds g in [1,7-rho] (28) + straddle
//   g=2048 (8, first-half blocks only).       [coverage verified R8]
// Cross blocks: 4 src rows x full trgt half.
// NOTE (R5/R9 lessons): NO cross-block fusion of the final reduce.
//   - __threadfence per block = L2 writeback storm (+70us, R5)
//   - single-address atomic chain: 2048 RMW x ~10ns serialized (+16us, R9)
//   The 1-block final_kernel node is cheaper than either.
__global__ __launch_bounds__(256, 8) void pair_kernel(const float* __restrict__ ff,
                                                      const double* __restrict__ pm,
                                                      double* __restrict__ partials) {
    __shared__ float  fs[B];       // 16 KB raw half
    __shared__ float  sclS;
    __shared__ double wred[4];
    const int tid = threadIdx.x;
    const int bid = blockIdx.x;
    const bool same = bid < SAME_BLOCKS;
    const int  r0g  = same ? (bid << 3) : 0;
    const float* src = same ? (ff + (r0g & 4096)) : (ff + B);

    {   // stage 16 KB (raw, scale applied at fragment load)
        const float4* s4 = (const float4*)src;
        float4* d4 = (float4*)fs;
        #pragma unroll
        for (int k = 0; k < 4; ++k) d4[tid + 256 * k] = s4[tid + 256 * k];
    }
    if (tid < 64) {   // wave 0: scl from gram moments, hidden under staging
        double s = pm[tid];
        #pragma unroll
        for (int msk = 2; msk <= 32; msk <<= 1) s += __shfl_xor(s, msk);
        const double o = __shfl_xor(s, 1);     // lane0: s=sum, o=sumsq
        if (tid == 0) {
            const double m1 = s * (1.0 / NF);
            const double m2 = o * (1.0 / NF);
            const double Dm = 2.0 * (m2 - m1 * m1);
            sclS = (float)sqrt(LOG2E / (4.0 * Dm));
        }
    }
    __syncthreads();
    const float scl = sclS;

    v2f a1 = {0.f,0.f}, a2 = {0.f,0.f}, a3 = {0.f,0.f};
    v2f n1 = {0.f,0.f}, n2 = {0.f,0.f}, n3 = {0.f,0.f};

    if (same) {
        const int r0l = r0g & 4095;            // multiple of 8
        v2f fi[4];                             // 8 rows, pre-scaled
        #pragma unroll
        for (int q = 0; q < 4; ++q) {
            fi[q].x = fs[r0l + 2 * q]     * scl;
            fi[q].y = fs[r0l + 2 * q + 1] * scl;
        }
        const int c0 = 8 + (tid << 3);         // 8 c-values, c in [8,2055]
        const int j0 = (r0l + c0) & 4095;      // 8-aligned -> aligned b128
        float vj[8], vjs[8];
        *(float4*)&vj[0] = *(const float4*)&fs[j0];
        *(float4*)&vj[4] = *(const float4*)&fs[j0 + 4];
        #pragma unroll
        for (int e = 0; e < 8; ++e) vjs[e] = vj[e] * scl;
        #pragma unroll
        for (int e = 0; e < 8; ++e) {          // fully uniform main loop
            v2f vv; vv.x = vjs[e]; vv.y = vjs[e];
            kern_b4(fi[0] - vv, fi[1] - vv, fi[2] - vv, fi[3] - vv, a1, a2, a3);
        }
        if (tid < 18) {
            // subtract the 36 over-counted pairs: c=2048+m (m<8), rho<=m
            v2f d;
            #pragma unroll
            for (int hp = 0; hp < 2; ++hp) {
                const int idx = 2 * tid + hp;              // [0,36)
                const int m   = (int)((sqrtf((float)(8 * idx + 1)) - 1.0f) * 0.5f);
                const int rho = idx - ((m * (m + 1)) >> 1);
                const float dv = (fs[r0l + rho] - fs[(r0l + 2048 + m) & 4095]) * scl;
                if (hp == 0) d.x = dv; else d.y = dv;
            }
            kern_d(d, n1, n2, n3);
            // add: 28 intra-block triangle (g in [1,7-rho]) + 8 straddle g=2048
            v2f d2;
            #pragma unroll
            for (int hp = 0; hp < 2; ++hp) {
                const int idx = 2 * tid + hp;              // [0,36)
                float dv;
                if (idx < 28) {
                    const int m   = (int)((1.0f + sqrtf((float)(1 + 8 * idx))) * 0.5f);
                    const int g   = idx - ((m * (m - 1)) >> 1) + 1;
                    const int rho = m - g;
                    dv = (fs[r0l + rho] - fs[r0l + rho + g]) * scl;
                } else {
                    const int rho = idx - 28;
                    dv = (r0l < 2048)
                       ? (fs[r0l + rho] - fs[r0l + rho + 2048]) * scl : 1e18f;
                }
                if (hp == 0) d2.x = dv; else d2.y = dv;
            }
            kern_d(d2, a1, a2, a3);
        }
    } else {
        const int r0c = (bid - SAME_BLOCKS) << 2;  // 4 src rows
        v2f fi[2];
        #pragma unroll
        for (int q = 0; q < 2; ++q) {
            fi[q].x = ff[r0c + 2 * q]     * scl;
            fi[q].y = ff[r0c + 2 * q + 1] * scl;
        }
        const int c0 = tid << 4;               // 16 contiguous trgt values
        float vj[16], vjs[16];
        #pragma unroll
        for (int k = 0; k < 4; ++k)
            *(float4*)&vj[4 * k] = *(const float4*)&fs[c0 + 4 * k];
        #pragma unroll
        for (int e = 0; e < 16; ++e) vjs[e] = vj[e] * scl;
        #pragma unroll
        for (int e = 0; e < 16; e += 2) {      // 2 e's x 2 rows = batch of 4
            v2f v0, v1;
            v0.x = vjs[e];     v0.y = vjs[e];
            v1.x = vjs[e + 1]; v1.y = vjs[e + 1];
            kern_b4(fi[0] - v0, fi[1] - v0, fi[0] - v1, fi[1] - v1, a1, a2, a3);
        }
    }

    // block reduce: f64 convert, in-wave butterfly, 4 wave-partials via LDS
    double t = (((double)a1.x + (double)a1.y) + ((double)a2.x + (double)a2.y)
             +  ((double)a3.x + (double)a3.y))
             - (((double)n1.x + (double)n1.y) + ((double)n2.x + (double)n2.y)
             +  ((double)n3.x + (double)n3.y));
    #pragma unroll
    for (int msk = 1; msk < 64; msk <<= 1) t += __shfl_xor(t, msk);
    if ((tid & 63) == 0) wred[tid >> 6] = t;
    __syncthreads();
    if (tid == 0) partials[bid] = (wred[0] + wred[1]) + (wred[2] + wred[3]);
}

// ---------------- K3: deterministic final reduce + loss --------------------
__global__ __launch_bounds__(256) void final_kernel(const double* __restrict__ partials,
                                                    float* __restrict__ out) {
    __shared__ double rs[256], rc[256];
    const int tid = threadIdx.x;
    double a = 0.0, b = 0.0;
    for (int i = tid; i < SAME_BLOCKS; i += 256)  a += partials[i];
    for (int i = tid; i < CROSS_BLOCKS; i += 256) b += partials[SAME_BLOCKS + i];
    rs[tid] = a; rc[tid] = b;
    __syncthreads();
    for (int off = 128; off > 0; off >>= 1) {
        if (tid < off) { rs[tid] += rs[tid + off]; rc[tid] += rc[tid + off]; }
        __syncthreads();
    }
    if (tid == 0) {
        const double S_same  = 2.0 * rs[0];   // unordered -> ordered
        const double S_cross = 2.0 * rc[0];   // one direction -> both
        const double bb = (double)B;
        const double loss = S_same / (bb * (bb - 1.0))
                          - S_cross / (bb * bb)
                          + 2.0 / (bb - 1.0);
        out[0] = (float)loss;
    }
}

extern "C" void kernel_launch(void* const* d_in, const int* in_sizes, int n_in,
                              void* d_out, int out_size, void* d_ws, size_t ws_size,
                              hipStream_t stream) {
    const float* feats = (const float*)d_in[0];
    float* out = (float*)d_out;
    double* ws = (double*)d_ws;

    double* pm       = ws;                         // 64 doubles
    double* partials = ws + 64;                    // 2048 doubles
    float*  ff       = (float*)(ws + 64 + 2048);   // 8192 floats

    gram_kernel <<<GRAM_BLOCKS, 256, 0, stream>>>(feats, ff, pm);
    pair_kernel <<<PAIR_BLOCKS, 256, 0, stream>>>(ff, pm, partials);
    final_kernel<<<1,           256, 0, stream>>>(partials, out);
}